// Round 1
// baseline (36071.237 us; speedup 1.0000x reference)
//
#include <hip/hip_runtime.h>
#include <hip/hip_bf16.h>

// EdgeConv block: B=8 clouds, N=4096 pts, K=20 nn, C_IN=64, C_OUT=128.
// Pipeline: k_sq -> k_wt -> k_knn (partial top-20, S=2 candidate split)
//           -> k_merge -> k_edge (gather + MFMA MLP1 + LN + MFMA MLP2 + LN + max + residual)

#define NB 8
#define NPTS 4096
#define KNN 20
#define CIN 64
#define COUT 128
#define NTOT (NB * NPTS)       // 32768
#define NEDGE (NTOT * KNN)     // 655360
#define LDA 136                // bf16 row stride (128 + 8 pad) -> 272 B

typedef short bf16x8 __attribute__((ext_vector_type(8)));
typedef float f32x4 __attribute__((ext_vector_type(4)));

__device__ __forceinline__ unsigned short f2bf(float f) {
    union { float f; unsigned u; } v; v.f = f;
    unsigned r = v.u + 0x7FFFu + ((v.u >> 16) & 1u);   // RTNE
    return (unsigned short)(r >> 16);
}
__device__ __forceinline__ float bf2f(unsigned short s) {
    union { unsigned u; float f; } v; v.u = ((unsigned)s) << 16;
    return v.f;
}

// ---------------- sq[n] = sum_c x[n][c]^2 ----------------
__global__ __launch_bounds__(256) void k_sq(const float* __restrict__ x, float* __restrict__ sq) {
    int t = threadIdx.x;
    int n = blockIdx.x * 4 + (t >> 6);
    int lane = t & 63;
    float v = x[n * 64 + lane];
    float s = v * v;
#pragma unroll
    for (int m = 32; m >= 1; m >>= 1) s += __shfl_xor(s, m);
    if (lane == 0) sq[n] = s;
}

// ---------------- transpose W1,W2 -> bf16 [d][c] ----------------
__global__ __launch_bounds__(256) void k_wt(const float* __restrict__ W1, const float* __restrict__ W2,
                                            unsigned short* __restrict__ w1t, unsigned short* __restrict__ w2t) {
    int id = blockIdx.x * 256 + threadIdx.x;   // 0..32767
    if (id < 16384) {
        int c = id >> 7, d = id & 127;
        w1t[d * 128 + c] = f2bf(W1[id]);
    } else {
        int i2 = id - 16384;
        int c = i2 >> 7, d = i2 & 127;
        w2t[d * 128 + c] = f2bf(W2[i2]);
    }
}

// ---------------- KNN: per (cloud, 64-query block, half of candidates) ----------------
// Writes sorted partial top-20 (d, global idx) per (query, s).
__global__ __launch_bounds__(256) void k_knn(const float* __restrict__ x, const float* __restrict__ sq,
                                             float* __restrict__ part_d, int* __restrict__ part_i) {
    int s  = blockIdx.x & 1;
    int qb = (blockIdx.x >> 1) & 63;
    int b  = blockIdx.x >> 7;
    int t  = threadIdx.x;
    int n0  = b * NPTS + qb * 64;      // query base (global id)
    int cb0 = b * NPTS + s * 2048;     // candidate base (global id)

    __shared__ union {
        struct { float Qt[64][68]; float Ct[64][68]; float D2[64][65]; float sqQ[64]; float sqC[64]; } a;
        struct { float md[64][80]; int mi[64][80]; } m;   // merge-phase reuse
    } sm;

    // stage Qt[c][q] (transposed)
    {
        int q = t >> 2, cg = (t & 3) * 16;
        const float* xq = x + (size_t)(n0 + q) * 64 + cg;
#pragma unroll
        for (int i = 0; i < 4; ++i) {
            float4 v = *(const float4*)(xq + i * 4);
            sm.a.Qt[cg + i * 4 + 0][q] = v.x;
            sm.a.Qt[cg + i * 4 + 1][q] = v.y;
            sm.a.Qt[cg + i * 4 + 2][q] = v.z;
            sm.a.Qt[cg + i * 4 + 3][q] = v.w;
        }
    }
    if (t < 64) sm.a.sqQ[t] = sq[n0 + t];

    float kd[KNN]; int ki[KNN];
#pragma unroll
    for (int p = 0; p < KNN; ++p) { kd[p] = 3.4e38f; ki[p] = 0x7fffffff; }

    int tq = t & 15, tc = t >> 4;      // 4x4 register tile coords
    int srow = t & 63, squad = t >> 6; // scan-phase coords

    for (int mt = 0; mt < 32; ++mt) {
        int cb = cb0 + mt * 64;
        // stage Ct[c][m] (transposed)
        {
            int mm = t >> 2, cg = (t & 3) * 16;
            const float* xc = x + (size_t)(cb + mm) * 64 + cg;
#pragma unroll
            for (int i = 0; i < 4; ++i) {
                float4 v = *(const float4*)(xc + i * 4);
                sm.a.Ct[cg + i * 4 + 0][mm] = v.x;
                sm.a.Ct[cg + i * 4 + 1][mm] = v.y;
                sm.a.Ct[cg + i * 4 + 2][mm] = v.z;
                sm.a.Ct[cg + i * 4 + 3][mm] = v.w;
            }
        }
        if (t < 64) sm.a.sqC[t] = sq[cb + t];
        __syncthreads();

        float acc[4][4];
#pragma unroll
        for (int i = 0; i < 4; ++i)
#pragma unroll
            for (int j = 0; j < 4; ++j) acc[i][j] = 0.f;

#pragma unroll 4
        for (int c = 0; c < 64; ++c) {
            float4 a = *(const float4*)&sm.a.Qt[c][tq * 4];
            float4 bb = *(const float4*)&sm.a.Ct[c][tc * 4];
            acc[0][0] += a.x * bb.x; acc[0][1] += a.x * bb.y; acc[0][2] += a.x * bb.z; acc[0][3] += a.x * bb.w;
            acc[1][0] += a.y * bb.x; acc[1][1] += a.y * bb.y; acc[1][2] += a.y * bb.z; acc[1][3] += a.y * bb.w;
            acc[2][0] += a.z * bb.x; acc[2][1] += a.z * bb.y; acc[2][2] += a.z * bb.z; acc[2][3] += a.z * bb.w;
            acc[3][0] += a.w * bb.x; acc[3][1] += a.w * bb.y; acc[3][2] += a.w * bb.z; acc[3][3] += a.w * bb.w;
        }
        // d2 = sq[q] + sq[m] - 2*dot
        float sqq[4], sqc[4];
#pragma unroll
        for (int i = 0; i < 4; ++i) { sqq[i] = sm.a.sqQ[tq * 4 + i]; sqc[i] = sm.a.sqC[tc * 4 + i]; }
#pragma unroll
        for (int i = 0; i < 4; ++i)
#pragma unroll
            for (int j = 0; j < 4; ++j)
                sm.a.D2[tq * 4 + i][tc * 4 + j] = sqq[i] + sqc[j] - 2.0f * acc[i][j];
        __syncthreads();

        // scan: thread owns query srow, candidate quarter squad
#pragma unroll
        for (int i = 0; i < 16; ++i) {
            int ml = squad * 16 + i;
            float d = sm.a.D2[srow][ml];
            int gid = cb + ml;
            if (d < kd[KNN - 1] || (d == kd[KNN - 1] && gid < ki[KNN - 1])) {
                kd[KNN - 1] = d; ki[KNN - 1] = gid;
#pragma unroll
                for (int p = KNN - 1; p > 0; --p) {
                    bool sw = (kd[p] < kd[p - 1]) || (kd[p] == kd[p - 1] && ki[p] < ki[p - 1]);
                    if (sw) {
                        float td = kd[p]; kd[p] = kd[p - 1]; kd[p - 1] = td;
                        int ti = ki[p]; ki[p] = ki[p - 1]; ki[p - 1] = ti;
                    }
                }
            }
        }
        // next iteration's staging barrier makes scans complete before D2 is rewritten
    }

    __syncthreads();   // before union reuse
#pragma unroll
    for (int p = 0; p < KNN; ++p) {
        sm.m.md[srow][squad * KNN + p] = kd[p];
        sm.m.mi[srow][squad * KNN + p] = ki[p];
    }
    __syncthreads();
    if (t < 64) {
        int ptr[4] = {0, 0, 0, 0};
        int nq = n0 + t;
        float* outd = part_d + ((size_t)nq * 2 + s) * KNN;
        int*   outi = part_i + ((size_t)nq * 2 + s) * KNN;
        for (int o = 0; o < KNN; ++o) {
            float bd = 3.5e38f; int bi = 0x7fffffff; int bq = 0;
#pragma unroll
            for (int u = 0; u < 4; ++u) {
                if (ptr[u] < KNN) {
                    float d = sm.m.md[t][u * KNN + ptr[u]];
                    int ii  = sm.m.mi[t][u * KNN + ptr[u]];
                    if (d < bd || (d == bd && ii < bi)) { bd = d; bi = ii; bq = u; }
                }
            }
            outd[o] = bd; outi[o] = bi; ptr[bq]++;
        }
    }
}

// ---------------- merge S=2 partial lists -> knn_idx ----------------
__global__ __launch_bounds__(256) void k_merge(const float* __restrict__ part_d, const int* __restrict__ part_i,
                                               int* __restrict__ knn_idx) {
    int nq = blockIdx.x * 256 + threadIdx.x;   // 0..32767
    const float* d0 = part_d + (size_t)nq * 40;
    const int*   i0 = part_i + (size_t)nq * 40;
    int p0 = 0, p1 = 0;
    for (int o = 0; o < KNN; ++o) {
        float da = d0[p0];      int ia = i0[p0];
        float db = d0[20 + p1]; int ib = i0[20 + p1];
        bool ta = (da < db) || (da == db && ia < ib);
        knn_idx[(size_t)nq * KNN + o] = ta ? ia : ib;
        if (ta) p0++; else p1++;
    }
}

// ---------------- fused edge MLP ----------------
__device__ __forceinline__ void gemm_tile(const unsigned short* A, const unsigned short* Bw,
                                          int wv, int lane, f32x4 acc[2][8]) {
    int lr = lane & 15, kg = lane >> 4;
#pragma unroll
    for (int ks = 0; ks < 4; ++ks) {
        int ko = ks * 32 + kg * 8;
        bf16x8 a0 = *(const bf16x8*)(A + (size_t)(wv * 32 + lr) * LDA + ko);
        bf16x8 a1 = *(const bf16x8*)(A + (size_t)(wv * 32 + 16 + lr) * LDA + ko);
#pragma unroll
        for (int nt = 0; nt < 8; ++nt) {
            bf16x8 bf = *(const bf16x8*)(Bw + (size_t)(nt * 16 + lr) * LDA + ko);
            acc[0][nt] = __builtin_amdgcn_mfma_f32_16x16x32_bf16(a0, bf, acc[0][nt], 0, 0, 0);
            acc[1][nt] = __builtin_amdgcn_mfma_f32_16x16x32_bf16(a1, bf, acc[1][nt], 0, 0, 0);
        }
    }
}

__device__ __forceinline__ void ln_relu_store(f32x4 acc[2][8], unsigned short* A, int wv, int lane,
                                              const float* __restrict__ bias, const float* __restrict__ g,
                                              const float* __restrict__ be) {
    int lc = lane & 15, kg = lane >> 4;
    float bv[8], gv[8], bev[8];
#pragma unroll
    for (int nt = 0; nt < 8; ++nt) {
        bv[nt]  = bias[nt * 16 + lc];
        gv[nt]  = g[nt * 16 + lc];
        bev[nt] = be[nt * 16 + lc];
    }
#pragma unroll
    for (int mt = 0; mt < 2; ++mt) {
#pragma unroll
        for (int j = 0; j < 4; ++j) {
            float v[8]; float s = 0.f, ss = 0.f;
#pragma unroll
            for (int nt = 0; nt < 8; ++nt) {
                v[nt] = acc[mt][nt][j] + bv[nt];
                s += v[nt]; ss += v[nt] * v[nt];
            }
#pragma unroll
            for (int m = 1; m < 16; m <<= 1) { s += __shfl_xor(s, m); ss += __shfl_xor(ss, m); }
            float mean = s * 0.0078125f;                       // /128
            float var  = ss * 0.0078125f - mean * mean;
            float rstd = rsqrtf(fmaxf(var, 0.f) + 1e-5f);
            int row = wv * 32 + mt * 16 + kg * 4 + j;          // verified C layout: col=lane&15, row=(lane>>4)*4+reg
#pragma unroll
            for (int nt = 0; nt < 8; ++nt) {
                float h = (v[nt] - mean) * rstd * gv[nt] + bev[nt];
                h = fmaxf(h, 0.f);
                A[(size_t)row * LDA + nt * 16 + lc] = f2bf(h);
            }
        }
    }
}

__global__ __launch_bounds__(320) void k_edge(const float* __restrict__ x, const int* __restrict__ knn_idx,
                                              const unsigned short* __restrict__ w1t, const unsigned short* __restrict__ w2t,
                                              const float* __restrict__ b1, const float* __restrict__ g1, const float* __restrict__ be1,
                                              const float* __restrict__ b2, const float* __restrict__ g2, const float* __restrict__ be2,
                                              const float* __restrict__ Wres, const float* __restrict__ bres,
                                              float* __restrict__ out) {
    __shared__ unsigned short A[160 * LDA];    // 43520 B: e-tile -> h1 -> h2
    __shared__ unsigned short Bw[128 * LDA];   // 34816 B: W1t then W2t
    int t = threadIdx.x;
    int blk = blockIdx.x;

    // gather edge features: rows = 8 points x 20 neighbors
    {
        int r = t >> 1, half = t & 1;
        int eg = blk * 160 + r;
        int n = eg / 20;                  // global point id (blocks own whole points)
        int j = knn_idx[eg];              // global neighbor id
        const float* xi = x + (size_t)n * 64;
        if (half == 0) {
#pragma unroll
            for (int i = 0; i < 16; ++i) {
                float4 v = *(const float4*)(xi + i * 4);
                ushort4 pk; pk.x = f2bf(v.x); pk.y = f2bf(v.y); pk.z = f2bf(v.z); pk.w = f2bf(v.w);
                *(ushort4*)&A[(size_t)r * LDA + i * 4] = pk;
            }
        } else {
            const float* xj = x + (size_t)j * 64;
#pragma unroll
            for (int i = 0; i < 16; ++i) {
                float4 vi = *(const float4*)(xi + i * 4);
                float4 vj = *(const float4*)(xj + i * 4);
                ushort4 pk; pk.x = f2bf(vj.x - vi.x); pk.y = f2bf(vj.y - vi.y);
                pk.z = f2bf(vj.z - vi.z); pk.w = f2bf(vj.w - vi.w);
                *(ushort4*)&A[(size_t)r * LDA + 64 + i * 4] = pk;
            }
        }
    }
    // load W1t
    for (int id = t; id < 2048; id += 320) {
        int row = id >> 4, ch = id & 15;
        *(uint4*)&Bw[(size_t)row * LDA + ch * 8] = *(const uint4*)(w1t + (size_t)row * 128 + ch * 8);
    }
    __syncthreads();

    int wv = t >> 6, lane = t & 63;
    f32x4 acc[2][8];
#pragma unroll
    for (int i = 0; i < 2; ++i)
#pragma unroll
        for (int j = 0; j < 8; ++j) acc[i][j] = (f32x4){0.f, 0.f, 0.f, 0.f};
    gemm_tile(A, Bw, wv, lane, acc);
    ln_relu_store(acc, A, wv, lane, b1, g1, be1);   // h1 -> A (own rows only)
    __syncthreads();                                // all GEMM1 B-reads done
    for (int id = t; id < 2048; id += 320) {
        int row = id >> 4, ch = id & 15;
        *(uint4*)&Bw[(size_t)row * LDA + ch * 8] = *(const uint4*)(w2t + (size_t)row * 128 + ch * 8);
    }
    __syncthreads();

    f32x4 acc2[2][8];
#pragma unroll
    for (int i = 0; i < 2; ++i)
#pragma unroll
        for (int j = 0; j < 8; ++j) acc2[i][j] = (f32x4){0.f, 0.f, 0.f, 0.f};
    gemm_tile(A, Bw, wv, lane, acc2);
    ln_relu_store(acc2, A, wv, lane, b2, g2, be2);  // h2 -> A (own rows only)
    __syncthreads();

    // max over K + residual projection + output
    for (int i = t; i < 1024; i += 320) {
        int p = i >> 7, c = i & 127;
        float mx = 0.f;                              // relu outputs >= 0
#pragma unroll
        for (int r = 0; r < 20; ++r)
            mx = fmaxf(mx, bf2f(A[(size_t)(p * 20 + r) * LDA + c]));
        int n = blk * 8 + p;
        float accr = bres[c];
        const float* xr = x + (size_t)n * 64;
#pragma unroll 8
        for (int cc = 0; cc < 64; ++cc) accr += xr[cc] * Wres[(size_t)cc * 128 + c];
        out[(size_t)n * 128 + c] = mx + accr;
    }
}

// ---------------- launcher ----------------
extern "C" void kernel_launch(void* const* d_in, const int* in_sizes, int n_in,
                              void* d_out, int out_size, void* d_ws, size_t ws_size,
                              hipStream_t stream) {
    const float* x    = (const float*)d_in[0];
    // d_in[1] = batch (contiguous equal segments) - unused
    const float* W1   = (const float*)d_in[2];
    const float* b1   = (const float*)d_in[3];
    const float* g1   = (const float*)d_in[4];
    const float* be1  = (const float*)d_in[5];
    const float* W2   = (const float*)d_in[6];
    const float* b2   = (const float*)d_in[7];
    const float* g2   = (const float*)d_in[8];
    const float* be2  = (const float*)d_in[9];
    const float* Wres = (const float*)d_in[10];
    const float* bres = (const float*)d_in[11];
    float* out = (float*)d_out;

    // workspace layout (small; big KNN partials live in d_out and are overwritten later)
    char* ws = (char*)d_ws;
    float* sq            = (float*)(ws);                    // 131072 B
    unsigned short* w1t  = (unsigned short*)(ws + 131072);  // 32768 B
    unsigned short* w2t  = (unsigned short*)(ws + 163840);  // 32768 B
    int* knn_idx         = (int*)(ws + 196608);             // 2621440 B  (total ~2.8 MB)

    // KNN partial lists staged inside d_out (16.78 MB >= 10.49 MB), consumed by k_merge
    float* part_d = (float*)d_out;                              // 32768*2*20*4 = 5242880 B
    int*   part_i = (int*)((char*)d_out + 5242880);             // 5242880 B

    k_sq   <<<dim3(NTOT / 4), dim3(256), 0, stream>>>(x, sq);
    k_wt   <<<dim3(128),      dim3(256), 0, stream>>>(W1, W2, w1t, w2t);
    k_knn  <<<dim3(1024),     dim3(256), 0, stream>>>(x, sq, part_d, part_i);
    k_merge<<<dim3(128),      dim3(256), 0, stream>>>(part_d, part_i, knn_idx);
    k_edge <<<dim3(NEDGE / 160), dim3(320), 0, stream>>>(x, knn_idx, w1t, w2t,
                                                         b1, g1, be1, b2, g2, be2,
                                                         Wres, bres, out);
}

// Round 2
// 1041.791 us; speedup vs baseline: 34.6243x; 34.6243x over previous
//
#include <hip/hip_runtime.h>
#include <hip/hip_bf16.h>

// EdgeConv block: B=8 clouds, N=4096 pts, K=20 nn, C_IN=64, C_OUT=128.
// Pipeline: k_sq -> k_wt -> k_knn (full 4096-candidate scan, register top-20,
//           in-block 4-way merge) -> k_edge (gather + MFMA MLP1 + LN + MFMA MLP2
//           + LN + max + residual)

#define NB 8
#define NPTS 4096
#define KNN 20
#define CIN 64
#define COUT 128
#define NTOT (NB * NPTS)       // 32768
#define NEDGE (NTOT * KNN)     // 655360
#define LDA 136                // bf16 row stride (128 + 8 pad) -> 272 B

typedef short bf16x8 __attribute__((ext_vector_type(8)));
typedef float f32x4 __attribute__((ext_vector_type(4)));

__device__ __forceinline__ unsigned short f2bf(float f) {
    union { float f; unsigned u; } v; v.f = f;
    unsigned r = v.u + 0x7FFFu + ((v.u >> 16) & 1u);   // RTNE
    return (unsigned short)(r >> 16);
}
__device__ __forceinline__ float bf2f(unsigned short s) {
    union { unsigned u; float f; } v; v.u = ((unsigned)s) << 16;
    return v.f;
}

// ---------------- sq[n] = sum_c x[n][c]^2 ----------------
__global__ __launch_bounds__(256) void k_sq(const float* __restrict__ x, float* __restrict__ sq) {
    int t = threadIdx.x;
    int n = blockIdx.x * 4 + (t >> 6);
    int lane = t & 63;
    float v = x[n * 64 + lane];
    float s = v * v;
#pragma unroll
    for (int m = 32; m >= 1; m >>= 1) s += __shfl_xor(s, m);
    if (lane == 0) sq[n] = s;
}

// ---------------- transpose W1,W2 -> bf16 [d][c] ----------------
__global__ __launch_bounds__(256) void k_wt(const float* __restrict__ W1, const float* __restrict__ W2,
                                            unsigned short* __restrict__ w1t, unsigned short* __restrict__ w2t) {
    int id = blockIdx.x * 256 + threadIdx.x;   // 0..32767
    if (id < 16384) {
        int c = id >> 7, d = id & 127;
        w1t[d * 128 + c] = f2bf(W1[id]);
    } else {
        int i2 = id - 16384;
        int c = i2 >> 7, d = i2 & 127;
        w2t[d * 128 + c] = f2bf(W2[i2]);
    }
}

// ---------------- KNN: one block per (cloud, 64-query block), all 4096 candidates ----
// Unsorted register top-20 + running kmax: accept test is 1 compare; on accept,
// replace first slot equal to kmax (static indices only -> no scratch), then
// recompute kmax. In-block 4-way merge via LDS, writes knn_idx directly.
__global__ __launch_bounds__(256, 3) void k_knn(const float* __restrict__ x, const float* __restrict__ sq,
                                                int* __restrict__ knn_idx) {
    int qb = blockIdx.x & 63;
    int b  = blockIdx.x >> 6;
    int t  = threadIdx.x;
    int n0  = b * NPTS + qb * 64;      // query base (global id)
    int cb0 = b * NPTS;                // candidate base (global id)

    __shared__ union {
        struct { float Qt[64][68]; float Ct[64][68]; float D2[64][65]; float sqQ[64]; float sqC[64]; } a;
        struct { float md[256][21]; int mi[256][21]; } m;   // merge-phase reuse (stride 21: conflict-free)
    } sm;

    // stage Qt[c][q] (transposed)
    {
        int q = t >> 2, cg = (t & 3) * 16;
        const float* xq = x + (size_t)(n0 + q) * 64 + cg;
#pragma unroll
        for (int i = 0; i < 4; ++i) {
            float4 v = *(const float4*)(xq + i * 4);
            sm.a.Qt[cg + i * 4 + 0][q] = v.x;
            sm.a.Qt[cg + i * 4 + 1][q] = v.y;
            sm.a.Qt[cg + i * 4 + 2][q] = v.z;
            sm.a.Qt[cg + i * 4 + 3][q] = v.w;
        }
    }
    if (t < 64) sm.a.sqQ[t] = sq[n0 + t];

    float kd[KNN]; int ki[KNN];
#pragma unroll
    for (int p = 0; p < KNN; ++p) { kd[p] = 3.4e38f; ki[p] = 0; }
    float kmax = 3.4e38f;

    int tq = t & 15, tc = t >> 4;      // 4x4 register tile coords
    int srow = t & 63, squad = t >> 6; // scan-phase coords

#pragma unroll 1
    for (int mt = 0; mt < 64; ++mt) {
        int cb = cb0 + mt * 64;
        // stage Ct[c][m] (transposed)
        {
            int mm = t >> 2, cg = (t & 3) * 16;
            const float* xc = x + (size_t)(cb + mm) * 64 + cg;
#pragma unroll
            for (int i = 0; i < 4; ++i) {
                float4 v = *(const float4*)(xc + i * 4);
                sm.a.Ct[cg + i * 4 + 0][mm] = v.x;
                sm.a.Ct[cg + i * 4 + 1][mm] = v.y;
                sm.a.Ct[cg + i * 4 + 2][mm] = v.z;
                sm.a.Ct[cg + i * 4 + 3][mm] = v.w;
            }
        }
        if (t < 64) sm.a.sqC[t] = sq[cb + t];
        __syncthreads();   // staging done; also: all waves finished scanning old D2

        float acc[4][4];
#pragma unroll
        for (int i = 0; i < 4; ++i)
#pragma unroll
            for (int j = 0; j < 4; ++j) acc[i][j] = 0.f;

#pragma unroll 4
        for (int c = 0; c < 64; ++c) {
            float4 a = *(const float4*)&sm.a.Qt[c][tq * 4];
            float4 bb = *(const float4*)&sm.a.Ct[c][tc * 4];
            acc[0][0] += a.x * bb.x; acc[0][1] += a.x * bb.y; acc[0][2] += a.x * bb.z; acc[0][3] += a.x * bb.w;
            acc[1][0] += a.y * bb.x; acc[1][1] += a.y * bb.y; acc[1][2] += a.y * bb.z; acc[1][3] += a.y * bb.w;
            acc[2][0] += a.z * bb.x; acc[2][1] += a.z * bb.y; acc[2][2] += a.z * bb.z; acc[2][3] += a.z * bb.w;
            acc[3][0] += a.w * bb.x; acc[3][1] += a.w * bb.y; acc[3][2] += a.w * bb.z; acc[3][3] += a.w * bb.w;
        }
        // d2 = sq[q] + sq[m] - 2*dot
        float sqq[4], sqc[4];
#pragma unroll
        for (int i = 0; i < 4; ++i) { sqq[i] = sm.a.sqQ[tq * 4 + i]; sqc[i] = sm.a.sqC[tc * 4 + i]; }
#pragma unroll
        for (int i = 0; i < 4; ++i)
#pragma unroll
            for (int j = 0; j < 4; ++j)
                sm.a.D2[tq * 4 + i][tc * 4 + j] = sqq[i] + sqc[j] - 2.0f * acc[i][j];
        __syncthreads();

        // scan: thread owns query srow, candidate quarter squad
#pragma unroll 1
        for (int i = 0; i < 16; ++i) {
            int ml = squad * 16 + i;
            float d = sm.a.D2[srow][ml];
            if (d < kmax) {
                int gid = cb + ml;
                bool done = false;
#pragma unroll
                for (int p = 0; p < KNN; ++p) {
                    bool repl = (!done) && (kd[p] == kmax);
                    kd[p] = repl ? d : kd[p];
                    ki[p] = repl ? gid : ki[p];
                    done = done || repl;
                }
                float nm = kd[0];
#pragma unroll
                for (int p = 1; p < KNN; ++p) nm = fmaxf(nm, kd[p]);
                kmax = nm;
            }
        }
        // next iteration's staging barrier guarantees scans complete before D2 rewrite
    }

    __syncthreads();   // before union reuse
#pragma unroll
    for (int p = 0; p < KNN; ++p) {
        sm.m.md[t][p] = kd[p];
        sm.m.mi[t][p] = ki[p];
    }
    __syncthreads();
    if (t < 64) {
        // merge the 4 per-squad lists for query t: top-20 of 80 (disjoint candidate sets)
        float kd2[KNN]; int ki2[KNN];
#pragma unroll
        for (int p = 0; p < KNN; ++p) { kd2[p] = 3.4e38f; ki2[p] = 0; }
        float kmax2 = 3.4e38f;
#pragma unroll 1
        for (int e = 0; e < 80; ++e) {
            int u = e >> 4 & 3;  // interleave not needed; just linear over 4 lists
            int pp = e % KNN;
            int lst = (e / KNN) * 64 + t;
            float d = sm.m.md[lst][pp];
            if (d < kmax2) {
                int gid = sm.m.mi[lst][pp];
                bool done = false;
#pragma unroll
                for (int p = 0; p < KNN; ++p) {
                    bool repl = (!done) && (kd2[p] == kmax2);
                    kd2[p] = repl ? d : kd2[p];
                    ki2[p] = repl ? gid : ki2[p];
                    done = done || repl;
                }
                float nm = kd2[0];
#pragma unroll
                for (int p = 1; p < KNN; ++p) nm = fmaxf(nm, kd2[p]);
                kmax2 = nm;
            }
            (void)u;
        }
        int* outp = knn_idx + (size_t)(n0 + t) * KNN;
#pragma unroll
        for (int p = 0; p < KNN; ++p) outp[p] = ki2[p];
    }
}

// ---------------- fused edge MLP ----------------
__device__ __forceinline__ void gemm_tile(const unsigned short* A, const unsigned short* Bw,
                                          int wv, int lane, f32x4 acc[2][8]) {
    int lr = lane & 15, kg = lane >> 4;
#pragma unroll
    for (int ks = 0; ks < 4; ++ks) {
        int ko = ks * 32 + kg * 8;
        bf16x8 a0 = *(const bf16x8*)(A + (size_t)(wv * 32 + lr) * LDA + ko);
        bf16x8 a1 = *(const bf16x8*)(A + (size_t)(wv * 32 + 16 + lr) * LDA + ko);
#pragma unroll
        for (int nt = 0; nt < 8; ++nt) {
            bf16x8 bf = *(const bf16x8*)(Bw + (size_t)(nt * 16 + lr) * LDA + ko);
            acc[0][nt] = __builtin_amdgcn_mfma_f32_16x16x32_bf16(a0, bf, acc[0][nt], 0, 0, 0);
            acc[1][nt] = __builtin_amdgcn_mfma_f32_16x16x32_bf16(a1, bf, acc[1][nt], 0, 0, 0);
        }
    }
}

__device__ __forceinline__ void ln_relu_store(f32x4 acc[2][8], unsigned short* A, int wv, int lane,
                                              const float* __restrict__ bias, const float* __restrict__ g,
                                              const float* __restrict__ be) {
    int lc = lane & 15, kg = lane >> 4;
    float bv[8], gv[8], bev[8];
#pragma unroll
    for (int nt = 0; nt < 8; ++nt) {
        bv[nt]  = bias[nt * 16 + lc];
        gv[nt]  = g[nt * 16 + lc];
        bev[nt] = be[nt * 16 + lc];
    }
#pragma unroll
    for (int mt = 0; mt < 2; ++mt) {
#pragma unroll
        for (int j = 0; j < 4; ++j) {
            float v[8]; float s = 0.f, ss = 0.f;
#pragma unroll
            for (int nt = 0; nt < 8; ++nt) {
                v[nt] = acc[mt][nt][j] + bv[nt];
                s += v[nt]; ss += v[nt] * v[nt];
            }
#pragma unroll
            for (int m = 1; m < 16; m <<= 1) { s += __shfl_xor(s, m); ss += __shfl_xor(ss, m); }
            float mean = s * 0.0078125f;                       // /128
            float var  = ss * 0.0078125f - mean * mean;
            float rstd = rsqrtf(fmaxf(var, 0.f) + 1e-5f);
            int row = wv * 32 + mt * 16 + kg * 4 + j;          // verified C layout: col=lane&15, row=(lane>>4)*4+reg
#pragma unroll
            for (int nt = 0; nt < 8; ++nt) {
                float h = (v[nt] - mean) * rstd * gv[nt] + bev[nt];
                h = fmaxf(h, 0.f);
                A[(size_t)row * LDA + nt * 16 + lc] = f2bf(h);
            }
        }
    }
}

__global__ __launch_bounds__(320) void k_edge(const float* __restrict__ x, const int* __restrict__ knn_idx,
                                              const unsigned short* __restrict__ w1t, const unsigned short* __restrict__ w2t,
                                              const float* __restrict__ b1, const float* __restrict__ g1, const float* __restrict__ be1,
                                              const float* __restrict__ b2, const float* __restrict__ g2, const float* __restrict__ be2,
                                              const float* __restrict__ Wres, const float* __restrict__ bres,
                                              float* __restrict__ out) {
    __shared__ unsigned short A[160 * LDA];    // 43520 B: e-tile -> h1 -> h2
    __shared__ unsigned short Bw[128 * LDA];   // 34816 B: W1t then W2t
    int t = threadIdx.x;
    int blk = blockIdx.x;

    // gather edge features: rows = 8 points x 20 neighbors
    {
        int r = t >> 1, half = t & 1;
        int eg = blk * 160 + r;
        int n = eg / 20;                  // global point id (blocks own whole points)
        int j = knn_idx[eg];              // global neighbor id
        const float* xi = x + (size_t)n * 64;
        if (half == 0) {
#pragma unroll
            for (int i = 0; i < 16; ++i) {
                float4 v = *(const float4*)(xi + i * 4);
                ushort4 pk; pk.x = f2bf(v.x); pk.y = f2bf(v.y); pk.z = f2bf(v.z); pk.w = f2bf(v.w);
                *(ushort4*)&A[(size_t)r * LDA + i * 4] = pk;
            }
        } else {
            const float* xj = x + (size_t)j * 64;
#pragma unroll
            for (int i = 0; i < 16; ++i) {
                float4 vi = *(const float4*)(xi + i * 4);
                float4 vj = *(const float4*)(xj + i * 4);
                ushort4 pk; pk.x = f2bf(vj.x - vi.x); pk.y = f2bf(vj.y - vi.y);
                pk.z = f2bf(vj.z - vi.z); pk.w = f2bf(vj.w - vi.w);
                *(ushort4*)&A[(size_t)r * LDA + 64 + i * 4] = pk;
            }
        }
    }
    // load W1t
    for (int id = t; id < 2048; id += 320) {
        int row = id >> 4, ch = id & 15;
        *(uint4*)&Bw[(size_t)row * LDA + ch * 8] = *(const uint4*)(w1t + (size_t)row * 128 + ch * 8);
    }
    __syncthreads();

    int wv = t >> 6, lane = t & 63;
    f32x4 acc[2][8];
#pragma unroll
    for (int i = 0; i < 2; ++i)
#pragma unroll
        for (int j = 0; j < 8; ++j) acc[i][j] = (f32x4){0.f, 0.f, 0.f, 0.f};
    gemm_tile(A, Bw, wv, lane, acc);
    ln_relu_store(acc, A, wv, lane, b1, g1, be1);   // h1 -> A (own rows only)
    __syncthreads();                                // all GEMM1 B-reads done
    for (int id = t; id < 2048; id += 320) {
        int row = id >> 4, ch = id & 15;
        *(uint4*)&Bw[(size_t)row * LDA + ch * 8] = *(const uint4*)(w2t + (size_t)row * 128 + ch * 8);
    }
    __syncthreads();

    f32x4 acc2[2][8];
#pragma unroll
    for (int i = 0; i < 2; ++i)
#pragma unroll
        for (int j = 0; j < 8; ++j) acc2[i][j] = (f32x4){0.f, 0.f, 0.f, 0.f};
    gemm_tile(A, Bw, wv, lane, acc2);
    ln_relu_store(acc2, A, wv, lane, b2, g2, be2);  // h2 -> A (own rows only)
    __syncthreads();

    // max over K + residual projection + output
    for (int i = t; i < 1024; i += 320) {
        int p = i >> 7, c = i & 127;
        float mx = 0.f;                              // relu outputs >= 0
#pragma unroll
        for (int r = 0; r < 20; ++r)
            mx = fmaxf(mx, bf2f(A[(size_t)(p * 20 + r) * LDA + c]));
        int n = blk * 8 + p;
        float accr = bres[c];
        const float* xr = x + (size_t)n * 64;
#pragma unroll 8
        for (int cc = 0; cc < 64; ++cc) accr += xr[cc] * Wres[(size_t)cc * 128 + c];
        out[(size_t)n * 128 + c] = mx + accr;
    }
}

// ---------------- launcher ----------------
extern "C" void kernel_launch(void* const* d_in, const int* in_sizes, int n_in,
                              void* d_out, int out_size, void* d_ws, size_t ws_size,
                              hipStream_t stream) {
    const float* x    = (const float*)d_in[0];
    // d_in[1] = batch (contiguous equal segments) - unused
    const float* W1   = (const float*)d_in[2];
    const float* b1   = (const float*)d_in[3];
    const float* g1   = (const float*)d_in[4];
    const float* be1  = (const float*)d_in[5];
    const float* W2   = (const float*)d_in[6];
    const float* b2   = (const float*)d_in[7];
    const float* g2   = (const float*)d_in[8];
    const float* be2  = (const float*)d_in[9];
    const float* Wres = (const float*)d_in[10];
    const float* bres = (const float*)d_in[11];
    float* out = (float*)d_out;

    char* ws = (char*)d_ws;
    float* sq            = (float*)(ws);                    // 131072 B
    unsigned short* w1t  = (unsigned short*)(ws + 131072);  // 32768 B
    unsigned short* w2t  = (unsigned short*)(ws + 163840);  // 32768 B
    int* knn_idx         = (int*)(ws + 196608);             // 2621440 B  (total ~2.8 MB)

    k_sq   <<<dim3(NTOT / 4), dim3(256), 0, stream>>>(x, sq);
    k_wt   <<<dim3(128),      dim3(256), 0, stream>>>(W1, W2, w1t, w2t);
    k_knn  <<<dim3(NB * 64),  dim3(256), 0, stream>>>(x, sq, knn_idx);
    k_edge <<<dim3(NEDGE / 160), dim3(320), 0, stream>>>(x, knn_idx, w1t, w2t,
                                                         b1, g1, be1, b2, g2, be2,
                                                         Wres, bres, out);
}

// Round 3
// 1033.631 us; speedup vs baseline: 34.8976x; 1.0079x over previous
//
#include <hip/hip_runtime.h>
#include <hip/hip_bf16.h>

// EdgeConv block: B=8 clouds, N=4096 pts, K=20 nn, C_IN=64, C_OUT=128.
// Pipeline: k_sq -> k_wt -> k_knn (full scan, register top-20, conflict-free LDS)
//           -> k_edge (gather + MFMA MLP1 + LN + MFMA MLP2 + LN + max + residual)

#define NB 8
#define NPTS 4096
#define KNN 20
#define CIN 64
#define COUT 128
#define NTOT (NB * NPTS)       // 32768
#define NEDGE (NTOT * KNN)     // 655360
#define LDA 136                // bf16 row stride (128 + 8 pad) -> 272 B

typedef short bf16x8 __attribute__((ext_vector_type(8)));
typedef float f32x4 __attribute__((ext_vector_type(4)));

__device__ __forceinline__ unsigned short f2bf(float f) {
    union { float f; unsigned u; } v; v.f = f;
    unsigned r = v.u + 0x7FFFu + ((v.u >> 16) & 1u);   // RTNE
    return (unsigned short)(r >> 16);
}
__device__ __forceinline__ float bf2f(unsigned short s) {
    union { unsigned u; float f; } v; v.u = ((unsigned)s) << 16;
    return v.f;
}

// ---------------- sq[n] = sum_c x[n][c]^2 ----------------
__global__ __launch_bounds__(256) void k_sq(const float* __restrict__ x, float* __restrict__ sq) {
    int t = threadIdx.x;
    int n = blockIdx.x * 4 + (t >> 6);
    int lane = t & 63;
    float v = x[n * 64 + lane];
    float s = v * v;
#pragma unroll
    for (int m = 32; m >= 1; m >>= 1) s += __shfl_xor(s, m);
    if (lane == 0) sq[n] = s;
}

// ---------------- transpose W1,W2 -> bf16 [d][c] ----------------
__global__ __launch_bounds__(256) void k_wt(const float* __restrict__ W1, const float* __restrict__ W2,
                                            unsigned short* __restrict__ w1t, unsigned short* __restrict__ w2t) {
    int id = blockIdx.x * 256 + threadIdx.x;   // 0..32767
    if (id < 16384) {
        int c = id >> 7, d = id & 127;
        w1t[d * 128 + c] = f2bf(W1[id]);
    } else {
        int i2 = id - 16384;
        int c = i2 >> 7, d = i2 & 127;
        w2t[d * 128 + c] = f2bf(W2[i2]);
    }
}

// ---------------- KNN: one block per (cloud, 64-query block), all 4096 candidates ----
// LDS layout tuned for zero/2-way bank conflicts:
//   - Qt/Ct staged transposed with k-rotation so the 4 lanes sharing q hit distinct banks
//   - D2 row stride 76 floats (=19*16B, odd granule): float4 writes, float4 scan reads
//   - scan loads 16 values as 4 independent ds_read_b128, then register-only compares
// Ranking value = sq[c] - 2*dot (sq[q] dropped: constant per query row).
__global__ __launch_bounds__(256, 3) void k_knn(const float* __restrict__ x, const float* __restrict__ sq,
                                                int* __restrict__ knn_idx) {
    int b  = blockIdx.x & 7;           // cloud -> XCD pinning (8 XCDs round-robin)
    int qb = blockIdx.x >> 3;          // 0..63
    int t  = threadIdx.x;
    int n0  = b * NPTS + qb * 64;      // query base (global id)
    int cb0 = b * NPTS;                // candidate base (global id)

    __shared__ union {
        struct { float Qt[64][68]; float Ct[64][68]; float D2[64][76]; float sqC[64]; } a;  // 54528 B
        struct { float md[256][21]; int mi[256][21]; } m;   // merge-phase reuse
    } sm;

    // stage Qt[c][q] (transposed, k-rotated stores: conflict-free)
    {
        int q = t >> 2, r0 = t & 3, cg = r0 * 16;
        const float* xq = x + (size_t)(n0 + q) * 64 + cg;
#pragma unroll
        for (int i = 0; i < 4; ++i) {
            float4 v = *(const float4*)(xq + i * 4);
            float vv[4] = {v.x, v.y, v.z, v.w};
#pragma unroll
            for (int k = 0; k < 4; ++k) {
                int kk = (k + r0) & 3;
                sm.a.Qt[cg + i * 4 + kk][q] = vv[kk];
            }
        }
    }

    float kd[KNN]; int ki[KNN];
#pragma unroll
    for (int p = 0; p < KNN; ++p) { kd[p] = 3.4e38f; ki[p] = 0; }
    float kmax = 3.4e38f;

    int tq = t & 15, tc = t >> 4;      // 4x4 register tile coords
    int srow = t & 63, squad = t >> 6; // scan-phase coords

#pragma unroll 1
    for (int mt = 0; mt < 64; ++mt) {
        int cb = cb0 + mt * 64;
        // stage Ct[c][m] (transposed, k-rotated)
        {
            int mm = t >> 2, r0 = t & 3, cg = r0 * 16;
            const float* xc = x + (size_t)(cb + mm) * 64 + cg;
#pragma unroll
            for (int i = 0; i < 4; ++i) {
                float4 v = *(const float4*)(xc + i * 4);
                float vv[4] = {v.x, v.y, v.z, v.w};
#pragma unroll
                for (int k = 0; k < 4; ++k) {
                    int kk = (k + r0) & 3;
                    sm.a.Ct[cg + i * 4 + kk][mm] = vv[kk];
                }
            }
        }
        if (t < 64) sm.a.sqC[t] = sq[cb + t];
        __syncthreads();   // staging done; also: all threads passed previous scan

        float acc[4][4];
#pragma unroll
        for (int i = 0; i < 4; ++i)
#pragma unroll
            for (int j = 0; j < 4; ++j) acc[i][j] = 0.f;

#pragma unroll 4
        for (int c = 0; c < 64; ++c) {
            float4 a = *(const float4*)&sm.a.Qt[c][tq * 4];
            float4 bb = *(const float4*)&sm.a.Ct[c][tc * 4];
            acc[0][0] += a.x * bb.x; acc[0][1] += a.x * bb.y; acc[0][2] += a.x * bb.z; acc[0][3] += a.x * bb.w;
            acc[1][0] += a.y * bb.x; acc[1][1] += a.y * bb.y; acc[1][2] += a.y * bb.z; acc[1][3] += a.y * bb.w;
            acc[2][0] += a.z * bb.x; acc[2][1] += a.z * bb.y; acc[2][2] += a.z * bb.z; acc[2][3] += a.z * bb.w;
            acc[3][0] += a.w * bb.x; acc[3][1] += a.w * bb.y; acc[3][2] += a.w * bb.z; acc[3][3] += a.w * bb.w;
        }
        // rank value = sq[m] - 2*dot  (sq[q] constant per row -> dropped)
        float sqc[4];
#pragma unroll
        for (int j = 0; j < 4; ++j) sqc[j] = sm.a.sqC[tc * 4 + j];
#pragma unroll
        for (int i = 0; i < 4; ++i) {
            float4 w;
            w.x = sqc[0] - 2.0f * acc[i][0];
            w.y = sqc[1] - 2.0f * acc[i][1];
            w.z = sqc[2] - 2.0f * acc[i][2];
            w.w = sqc[3] - 2.0f * acc[i][3];
            *(float4*)&sm.a.D2[tq * 4 + i][tc * 4] = w;
        }
        __syncthreads();

        // scan: thread owns query srow, candidate quarter squad.
        // 4 independent b128 loads -> register scan (no serial LDS latency chain).
        float v[16];
#pragma unroll
        for (int u = 0; u < 4; ++u)
            *(float4*)&v[u * 4] = *(const float4*)&sm.a.D2[srow][squad * 16 + u * 4];
#pragma unroll
        for (int i = 0; i < 16; ++i) {
            if (v[i] < kmax) {
                int gid = cb + squad * 16 + i;
                bool done = false;
#pragma unroll
                for (int p = 0; p < KNN; ++p) {
                    bool repl = (!done) && (kd[p] == kmax);
                    kd[p] = repl ? v[i] : kd[p];
                    ki[p] = repl ? gid : ki[p];
                    done = done || repl;
                }
                float nm = kd[0];
#pragma unroll
                for (int p = 1; p < KNN; ++p) nm = fmaxf(nm, kd[p]);
                kmax = nm;
            }
        }
        // next iteration's staging barrier guarantees scans complete before D2 rewrite
    }

    __syncthreads();   // before union reuse
#pragma unroll
    for (int p = 0; p < KNN; ++p) {
        sm.m.md[t][p] = kd[p];
        sm.m.mi[t][p] = ki[p];
    }
    __syncthreads();
    if (t < 64) {
        // merge the 4 per-squad lists for query t: top-20 of 80 (disjoint candidate sets)
        float kd2[KNN]; int ki2[KNN];
#pragma unroll
        for (int p = 0; p < KNN; ++p) { kd2[p] = 3.4e38f; ki2[p] = 0; }
        float kmax2 = 3.4e38f;
#pragma unroll 1
        for (int e = 0; e < 80; ++e) {
            int pp = e % KNN;
            int lst = (e / KNN) * 64 + t;
            float d = sm.m.md[lst][pp];
            if (d < kmax2) {
                int gid = sm.m.mi[lst][pp];
                bool done = false;
#pragma unroll
                for (int p = 0; p < KNN; ++p) {
                    bool repl = (!done) && (kd2[p] == kmax2);
                    kd2[p] = repl ? d : kd2[p];
                    ki2[p] = repl ? gid : ki2[p];
                    done = done || repl;
                }
                float nm = kd2[0];
#pragma unroll
                for (int p = 1; p < KNN; ++p) nm = fmaxf(nm, kd2[p]);
                kmax2 = nm;
            }
        }
        int* outp = knn_idx + (size_t)(n0 + t) * KNN;
#pragma unroll
        for (int p = 0; p < KNN; ++p) outp[p] = ki2[p];
    }
}

// ---------------- fused edge MLP ----------------
__device__ __forceinline__ void gemm_tile(const unsigned short* A, const unsigned short* Bw,
                                          int wv, int lane, f32x4 acc[2][8]) {
    int lr = lane & 15, kg = lane >> 4;
#pragma unroll
    for (int ks = 0; ks < 4; ++ks) {
        int ko = ks * 32 + kg * 8;
        bf16x8 a0 = *(const bf16x8*)(A + (size_t)(wv * 32 + lr) * LDA + ko);
        bf16x8 a1 = *(const bf16x8*)(A + (size_t)(wv * 32 + 16 + lr) * LDA + ko);
#pragma unroll
        for (int nt = 0; nt < 8; ++nt) {
            bf16x8 bf = *(const bf16x8*)(Bw + (size_t)(nt * 16 + lr) * LDA + ko);
            acc[0][nt] = __builtin_amdgcn_mfma_f32_16x16x32_bf16(a0, bf, acc[0][nt], 0, 0, 0);
            acc[1][nt] = __builtin_amdgcn_mfma_f32_16x16x32_bf16(a1, bf, acc[1][nt], 0, 0, 0);
        }
    }
}

__device__ __forceinline__ void ln_relu_store(f32x4 acc[2][8], unsigned short* A, int wv, int lane,
                                              const float* __restrict__ bias, const float* __restrict__ g,
                                              const float* __restrict__ be) {
    int lc = lane & 15, kg = lane >> 4;
    float bv[8], gv[8], bev[8];
#pragma unroll
    for (int nt = 0; nt < 8; ++nt) {
        bv[nt]  = bias[nt * 16 + lc];
        gv[nt]  = g[nt * 16 + lc];
        bev[nt] = be[nt * 16 + lc];
    }
#pragma unroll
    for (int mt = 0; mt < 2; ++mt) {
#pragma unroll
        for (int j = 0; j < 4; ++j) {
            float v[8]; float s = 0.f, ss = 0.f;
#pragma unroll
            for (int nt = 0; nt < 8; ++nt) {
                v[nt] = acc[mt][nt][j] + bv[nt];
                s += v[nt]; ss += v[nt] * v[nt];
            }
#pragma unroll
            for (int m = 1; m < 16; m <<= 1) { s += __shfl_xor(s, m); ss += __shfl_xor(ss, m); }
            float mean = s * 0.0078125f;                       // /128
            float var  = ss * 0.0078125f - mean * mean;
            float rstd = rsqrtf(fmaxf(var, 0.f) + 1e-5f);
            int row = wv * 32 + mt * 16 + kg * 4 + j;          // verified C layout: col=lane&15, row=(lane>>4)*4+reg
#pragma unroll
            for (int nt = 0; nt < 8; ++nt) {
                float h = (v[nt] - mean) * rstd * gv[nt] + bev[nt];
                h = fmaxf(h, 0.f);
                A[(size_t)row * LDA + nt * 16 + lc] = f2bf(h);
            }
        }
    }
}

__global__ __launch_bounds__(320) void k_edge(const float* __restrict__ x, const int* __restrict__ knn_idx,
                                              const unsigned short* __restrict__ w1t, const unsigned short* __restrict__ w2t,
                                              const float* __restrict__ b1, const float* __restrict__ g1, const float* __restrict__ be1,
                                              const float* __restrict__ b2, const float* __restrict__ g2, const float* __restrict__ be2,
                                              const float* __restrict__ Wres, const float* __restrict__ bres,
                                              float* __restrict__ out) {
    __shared__ unsigned short A[160 * LDA];    // 43520 B: e-tile -> h1 -> h2
    __shared__ unsigned short Bw[128 * LDA];   // 34816 B: W1t then W2t
    int t = threadIdx.x;
    int blk = blockIdx.x;

    // gather edge features: rows = 8 points x 20 neighbors
    {
        int r = t >> 1, half = t & 1;
        int eg = blk * 160 + r;
        int n = eg / 20;                  // global point id (blocks own whole points)
        int j = knn_idx[eg];              // global neighbor id
        const float* xi = x + (size_t)n * 64;
        if (half == 0) {
#pragma unroll
            for (int i = 0; i < 16; ++i) {
                float4 v = *(const float4*)(xi + i * 4);
                ushort4 pk; pk.x = f2bf(v.x); pk.y = f2bf(v.y); pk.z = f2bf(v.z); pk.w = f2bf(v.w);
                *(ushort4*)&A[(size_t)r * LDA + i * 4] = pk;
            }
        } else {
            const float* xj = x + (size_t)j * 64;
#pragma unroll
            for (int i = 0; i < 16; ++i) {
                float4 vi = *(const float4*)(xi + i * 4);
                float4 vj = *(const float4*)(xj + i * 4);
                ushort4 pk; pk.x = f2bf(vj.x - vi.x); pk.y = f2bf(vj.y - vi.y);
                pk.z = f2bf(vj.z - vi.z); pk.w = f2bf(vj.w - vi.w);
                *(ushort4*)&A[(size_t)r * LDA + 64 + i * 4] = pk;
            }
        }
    }
    // load W1t
    for (int id = t; id < 2048; id += 320) {
        int row = id >> 4, ch = id & 15;
        *(uint4*)&Bw[(size_t)row * LDA + ch * 8] = *(const uint4*)(w1t + (size_t)row * 128 + ch * 8);
    }
    __syncthreads();

    int wv = t >> 6, lane = t & 63;
    f32x4 acc[2][8];
#pragma unroll
    for (int i = 0; i < 2; ++i)
#pragma unroll
        for (int j = 0; j < 8; ++j) acc[i][j] = (f32x4){0.f, 0.f, 0.f, 0.f};
    gemm_tile(A, Bw, wv, lane, acc);
    ln_relu_store(acc, A, wv, lane, b1, g1, be1);   // h1 -> A (own rows only)
    __syncthreads();                                // all GEMM1 B-reads done
    for (int id = t; id < 2048; id += 320) {
        int row = id >> 4, ch = id & 15;
        *(uint4*)&Bw[(size_t)row * LDA + ch * 8] = *(const uint4*)(w2t + (size_t)row * 128 + ch * 8);
    }
    __syncthreads();

    f32x4 acc2[2][8];
#pragma unroll
    for (int i = 0; i < 2; ++i)
#pragma unroll
        for (int j = 0; j < 8; ++j) acc2[i][j] = (f32x4){0.f, 0.f, 0.f, 0.f};
    gemm_tile(A, Bw, wv, lane, acc2);
    ln_relu_store(acc2, A, wv, lane, b2, g2, be2);  // h2 -> A (own rows only)
    __syncthreads();

    // max over K + residual projection + output
    for (int i = t; i < 1024; i += 320) {
        int p = i >> 7, c = i & 127;
        float mx = 0.f;                              // relu outputs >= 0
#pragma unroll
        for (int r = 0; r < 20; ++r)
            mx = fmaxf(mx, bf2f(A[(size_t)(p * 20 + r) * LDA + c]));
        int n = blk * 8 + p;
        float accr = bres[c];
        const float* xr = x + (size_t)n * 64;
#pragma unroll 8
        for (int cc = 0; cc < 64; ++cc) accr += xr[cc] * Wres[(size_t)cc * 128 + c];
        out[(size_t)n * 128 + c] = mx + accr;
    }
}

// ---------------- launcher ----------------
extern "C" void kernel_launch(void* const* d_in, const int* in_sizes, int n_in,
                              void* d_out, int out_size, void* d_ws, size_t ws_size,
                              hipStream_t stream) {
    const float* x    = (const float*)d_in[0];
    // d_in[1] = batch (contiguous equal segments) - unused
    const float* W1   = (const float*)d_in[2];
    const float* b1   = (const float*)d_in[3];
    const float* g1   = (const float*)d_in[4];
    const float* be1  = (const float*)d_in[5];
    const float* W2   = (const float*)d_in[6];
    const float* b2   = (const float*)d_in[7];
    const float* g2   = (const float*)d_in[8];
    const float* be2  = (const float*)d_in[9];
    const float* Wres = (const float*)d_in[10];
    const float* bres = (const float*)d_in[11];
    float* out = (float*)d_out;

    char* ws = (char*)d_ws;
    float* sq            = (float*)(ws);                    // 131072 B
    unsigned short* w1t  = (unsigned short*)(ws + 131072);  // 32768 B
    unsigned short* w2t  = (unsigned short*)(ws + 163840);  // 32768 B
    int* knn_idx         = (int*)(ws + 196608);             // 2621440 B  (total ~2.8 MB)

    k_sq   <<<dim3(NTOT / 4), dim3(256), 0, stream>>>(x, sq);
    k_wt   <<<dim3(128),      dim3(256), 0, stream>>>(W1, W2, w1t, w2t);
    k_knn  <<<dim3(NB * 64),  dim3(256), 0, stream>>>(x, sq, knn_idx);
    k_edge <<<dim3(NEDGE / 160), dim3(320), 0, stream>>>(x, knn_idx, w1t, w2t,
                                                         b1, g1, be1, b2, g2, be2,
                                                         Wres, bres, out);
}

// Round 4
// 889.918 us; speedup vs baseline: 40.5332x; 1.1615x over previous
//
#include <hip/hip_runtime.h>
#include <hip/hip_bf16.h>

// EdgeConv block: B=8 clouds, N=4096 pts, K=20 nn, C_IN=64, C_OUT=128.
// Pipeline: k_prep (x -> bf16 hi/lo planes) -> k_sq -> k_wt
//   -> k_knn (MFMA split-bf16 distance scan, per-lane top-20, merge->24, exact fp32 recheck -> top-20 set)
//   -> k_edge (gather + MFMA MLP1 + LN + MFMA MLP2 + LN + max + residual)

#define NB 8
#define NPTS 4096
#define KNN 20
#define CIN 64
#define COUT 128
#define NTOT (NB * NPTS)       // 32768
#define NEDGE (NTOT * KNN)     // 655360
#define LDA 136                // bf16 row stride (128 + 8 pad) -> 272 B

typedef short bf16x8 __attribute__((ext_vector_type(8)));
typedef float f32x4 __attribute__((ext_vector_type(4)));

__device__ __forceinline__ unsigned short f2bf(float f) {
    union { float f; unsigned u; } v; v.f = f;
    unsigned r = v.u + 0x7FFFu + ((v.u >> 16) & 1u);   // RTNE
    return (unsigned short)(r >> 16);
}
__device__ __forceinline__ float bf2f(unsigned short s) {
    union { unsigned u; float f; } v; v.u = ((unsigned)s) << 16;
    return v.f;
}

// ---------------- x -> bf16 hi/lo planes ----------------
__global__ __launch_bounds__(256) void k_prep(const float* __restrict__ x,
                                              unsigned short* __restrict__ xhi,
                                              unsigned short* __restrict__ xlo) {
    int id = blockIdx.x * 2048 + threadIdx.x * 8;
    float4 v0 = *(const float4*)(x + id);
    float4 v1 = *(const float4*)(x + id + 4);
    float vs[8] = {v0.x, v0.y, v0.z, v0.w, v1.x, v1.y, v1.z, v1.w};
    unsigned short h[8], l[8];
#pragma unroll
    for (int i = 0; i < 8; ++i) {
        h[i] = f2bf(vs[i]);
        l[i] = f2bf(vs[i] - bf2f(h[i]));   // residual exactly representable in fp32
    }
    uint4 hp, lp;
    hp.x = h[0] | ((unsigned)h[1] << 16); hp.y = h[2] | ((unsigned)h[3] << 16);
    hp.z = h[4] | ((unsigned)h[5] << 16); hp.w = h[6] | ((unsigned)h[7] << 16);
    lp.x = l[0] | ((unsigned)l[1] << 16); lp.y = l[2] | ((unsigned)l[3] << 16);
    lp.z = l[4] | ((unsigned)l[5] << 16); lp.w = l[6] | ((unsigned)l[7] << 16);
    *(uint4*)(xhi + id) = hp;
    *(uint4*)(xlo + id) = lp;
}

// ---------------- sq[n] = sum_c x[n][c]^2 ----------------
__global__ __launch_bounds__(256) void k_sq(const float* __restrict__ x, float* __restrict__ sq) {
    int t = threadIdx.x;
    int n = blockIdx.x * 4 + (t >> 6);
    int lane = t & 63;
    float v = x[n * 64 + lane];
    float s = v * v;
#pragma unroll
    for (int m = 32; m >= 1; m >>= 1) s += __shfl_xor(s, m);
    if (lane == 0) sq[n] = s;
}

// ---------------- transpose W1,W2 -> bf16 [d][c] ----------------
__global__ __launch_bounds__(256) void k_wt(const float* __restrict__ W1, const float* __restrict__ W2,
                                            unsigned short* __restrict__ w1t, unsigned short* __restrict__ w2t) {
    int id = blockIdx.x * 256 + threadIdx.x;   // 0..32767
    if (id < 16384) {
        int c = id >> 7, d = id & 127;
        w1t[d * 128 + c] = f2bf(W1[id]);
    } else {
        int i2 = id - 16384;
        int c = i2 >> 7, d = i2 & 127;
        w2t[d * 128 + c] = f2bf(W2[i2]);
    }
}

// ---------------- KNN via MFMA ----------------
// Block: 256 thr = 4 waves; wave wv owns queries n0 + wv*16 + (lane&15).
// D[cand][query] = A(cands) x B(queries); per lane: 4 cands (rows kg*4+j) for 1 query.
// score = 0.5*sq_c - dot  (smaller = nearer); -0.5*sq_c folded into MFMA C-init.
// 3-pass split-bf16 (hi*hi + lo*hi + hi*lo); exact fp32 recheck of merged top-24.
__global__ __launch_bounds__(256) void k_knn(const float* __restrict__ x,
                                             const unsigned short* __restrict__ xhi,
                                             const unsigned short* __restrict__ xlo,
                                             const float* __restrict__ sq,
                                             int* __restrict__ knn_idx) {
    int b  = blockIdx.x & 7;           // cloud -> XCD pinning
    int qb = blockIdx.x >> 3;          // 0..63
    int t  = threadIdx.x;
    int wv = t >> 6, lane = t & 63;
    int lr = lane & 15, kg = lane >> 4;
    int n0  = b * NPTS + qb * 64;
    int cb0 = b * NPTS;

    // LDS: frag[f][lane*8] pre-packed in per-lane MFMA read order (linear, conflict-free)
    __shared__ union {
        unsigned short frag[8][512];   // 8 x 1KB: f = tt*4 + p*2 + kh
        float xq[64][68];              // exact-phase query cache (padded)
    } smA;
    __shared__ float md[64][81];
    __shared__ int   mi[64][81];
    __shared__ int   ci[64][24];
    __shared__ float ce[64][24];

    // query B-fragments (col = lane&15, k-slice kg*8), hi/lo x 2 K-halves
    int qg = n0 + wv * 16 + lr;
    bf16x8 qhi0 = *(const bf16x8*)(xhi + (size_t)qg * 64 + kg * 8);
    bf16x8 qhi1 = *(const bf16x8*)(xhi + (size_t)qg * 64 + 32 + kg * 8);
    bf16x8 qlo0 = *(const bf16x8*)(xlo + (size_t)qg * 64 + kg * 8);
    bf16x8 qlo1 = *(const bf16x8*)(xlo + (size_t)qg * 64 + 32 + kg * 8);

    float kd[KNN]; int ki[KNN];
#pragma unroll
    for (int p = 0; p < KNN; ++p) { kd[p] = 3.4e38f; ki[p] = 0; }
    float kmax = 3.4e38f;

    // wave's staging role: frags f0=2wv (kh=0), f1=2wv+1 (kh=1); tt=wv>>1, plane p=wv&1
    int stt = wv >> 1;
    const unsigned short* plane = (wv & 1) ? xlo : xhi;
    int f0 = 2 * wv, f1 = 2 * wv + 1;

    // preload iter 0
    const unsigned short* s0p = plane + (size_t)(cb0 + stt * 16 + lr) * 64 + kg * 8;
    uint4 g0 = *(const uint4*)s0p;
    uint4 g1 = *(const uint4*)(s0p + 32);
    float4 sqa = *(const float4*)&sq[cb0 + kg * 4];
    float4 sqb = *(const float4*)&sq[cb0 + 16 + kg * 4];

#pragma unroll 1
    for (int it = 0; it < 128; ++it) {
        int cb = cb0 + it * 32;
        __syncthreads();                       // (A) everyone done reading frag
        *(uint4*)&smA.frag[f0][lane * 8] = g0;
        *(uint4*)&smA.frag[f1][lane * 8] = g1;
        float4 s0c = sqa, s1c = sqb;
        __syncthreads();                       // (B) frag visible
        if (it + 1 < 128) {                    // issue next-iter loads; overlap with MFMA below
            const unsigned short* sp = plane + (size_t)(cb + 32 + stt * 16 + lr) * 64 + kg * 8;
            g0 = *(const uint4*)sp;
            g1 = *(const uint4*)(sp + 32);
            sqa = *(const float4*)&sq[cb + 32 + kg * 4];
            sqb = *(const float4*)&sq[cb + 48 + kg * 4];
        }

        bf16x8 A0 = *(const bf16x8*)&smA.frag[0][lane * 8];  // t0 hi k0
        bf16x8 A1 = *(const bf16x8*)&smA.frag[1][lane * 8];  // t0 hi k1
        bf16x8 A2 = *(const bf16x8*)&smA.frag[2][lane * 8];  // t0 lo k0
        bf16x8 A3 = *(const bf16x8*)&smA.frag[3][lane * 8];  // t0 lo k1
        bf16x8 A4 = *(const bf16x8*)&smA.frag[4][lane * 8];  // t1 hi k0
        bf16x8 A5 = *(const bf16x8*)&smA.frag[5][lane * 8];  // t1 hi k1
        bf16x8 A6 = *(const bf16x8*)&smA.frag[6][lane * 8];  // t1 lo k0
        bf16x8 A7 = *(const bf16x8*)&smA.frag[7][lane * 8];  // t1 lo k1

        f32x4 a00 = {-0.5f * s0c.x, -0.5f * s0c.y, -0.5f * s0c.z, -0.5f * s0c.w};
        f32x4 a01 = {0.f, 0.f, 0.f, 0.f};
        f32x4 a10 = {-0.5f * s1c.x, -0.5f * s1c.y, -0.5f * s1c.z, -0.5f * s1c.w};
        f32x4 a11 = {0.f, 0.f, 0.f, 0.f};
        // 4 independent chains of 3 MFMAs
        a00 = __builtin_amdgcn_mfma_f32_16x16x32_bf16(A0, qhi0, a00, 0, 0, 0);
        a10 = __builtin_amdgcn_mfma_f32_16x16x32_bf16(A4, qhi0, a10, 0, 0, 0);
        a01 = __builtin_amdgcn_mfma_f32_16x16x32_bf16(A1, qhi1, a01, 0, 0, 0);
        a11 = __builtin_amdgcn_mfma_f32_16x16x32_bf16(A5, qhi1, a11, 0, 0, 0);
        a00 = __builtin_amdgcn_mfma_f32_16x16x32_bf16(A2, qhi0, a00, 0, 0, 0);
        a10 = __builtin_amdgcn_mfma_f32_16x16x32_bf16(A6, qhi0, a10, 0, 0, 0);
        a01 = __builtin_amdgcn_mfma_f32_16x16x32_bf16(A3, qhi1, a01, 0, 0, 0);
        a11 = __builtin_amdgcn_mfma_f32_16x16x32_bf16(A7, qhi1, a11, 0, 0, 0);
        a00 = __builtin_amdgcn_mfma_f32_16x16x32_bf16(A0, qlo0, a00, 0, 0, 0);
        a10 = __builtin_amdgcn_mfma_f32_16x16x32_bf16(A4, qlo0, a10, 0, 0, 0);
        a01 = __builtin_amdgcn_mfma_f32_16x16x32_bf16(A1, qlo1, a01, 0, 0, 0);
        a11 = __builtin_amdgcn_mfma_f32_16x16x32_bf16(A5, qlo1, a11, 0, 0, 0);

#pragma unroll
        for (int j = 0; j < 4; ++j) {
            float sc = -(a00[j] + a01[j]);
            int cand = cb + kg * 4 + j;
            if (sc < kmax) {
                bool done = false;
#pragma unroll
                for (int p = 0; p < KNN; ++p) {
                    bool repl = (!done) && (kd[p] == kmax);
                    kd[p] = repl ? sc : kd[p];
                    ki[p] = repl ? cand : ki[p];
                    done = done || repl;
                }
                float nm = kd[0];
#pragma unroll
                for (int p = 1; p < KNN; ++p) nm = fmaxf(nm, kd[p]);
                kmax = nm;
            }
        }
#pragma unroll
        for (int j = 0; j < 4; ++j) {
            float sc = -(a10[j] + a11[j]);
            int cand = cb + 16 + kg * 4 + j;
            if (sc < kmax) {
                bool done = false;
#pragma unroll
                for (int p = 0; p < KNN; ++p) {
                    bool repl = (!done) && (kd[p] == kmax);
                    kd[p] = repl ? sc : kd[p];
                    ki[p] = repl ? cand : ki[p];
                    done = done || repl;
                }
                float nm = kd[0];
#pragma unroll
                for (int p = 1; p < KNN; ++p) nm = fmaxf(nm, kd[p]);
                kmax = nm;
            }
        }
    }

    __syncthreads();   // all frag reads done (smA reused as xq below)
    {
        int ql = wv * 16 + lr;
#pragma unroll
        for (int p = 0; p < KNN; ++p) {
            md[ql][kg * KNN + p] = kd[p];
            mi[ql][kg * KNN + p] = ki[p];
        }
    }
    __syncthreads();

    // merge->top24 (t<64) || stage xq fp32 (t>=64)
    if (t < 64) {
        float kdm[24]; int kim[24];
#pragma unroll
        for (int s = 0; s < 24; ++s) { kdm[s] = 3.4e38f; kim[s] = 0; }
        float km = 3.4e38f;
#pragma unroll 1
        for (int e = 0; e < 80; ++e) {
            float d = md[t][e];
            if (d < km) {
                int id = mi[t][e];
                bool done = false;
#pragma unroll
                for (int s = 0; s < 24; ++s) {
                    bool repl = (!done) && (kdm[s] == km);
                    kdm[s] = repl ? d : kdm[s];
                    kim[s] = repl ? id : kim[s];
                    done = done || repl;
                }
                float nm = kdm[0];
#pragma unroll
                for (int s = 1; s < 24; ++s) nm = fmaxf(nm, kdm[s]);
                km = nm;
            }
        }
#pragma unroll
        for (int s = 0; s < 24; ++s) ci[t][s] = kim[s];
    } else {
        for (int idx = t - 64; idx < 1024; idx += 192) {
            int q = idx >> 4, dg = idx & 15;
            *(float4*)&smA.xq[q][dg * 4] = *(const float4*)(x + (size_t)(n0 + q) * 64 + dg * 4);
        }
    }
    __syncthreads();

    // exact fp32 recheck: 4 threads/query x 6 cands
    {
        int q = t >> 2, sl = (t & 3) * 6;
#pragma unroll 1
        for (int u = 0; u < 6; ++u) {
            int cidx = ci[q][sl + u];
            const float* xc = x + (size_t)cidx * 64;
            float dot = 0.f;
#pragma unroll
            for (int g = 0; g < 16; ++g) {
                float4 a = *(const float4*)&smA.xq[q][g * 4];
                float4 bb = *(const float4*)(xc + g * 4);
                dot += a.x * bb.x + a.y * bb.y + a.z * bb.z + a.w * bb.w;
            }
            ce[q][sl + u] = 0.5f * sq[cidx] - dot;
        }
    }
    __syncthreads();

    // exclude the 4 lexicographically-largest (score, then higher idx) -> exact top-20 set
    if (t < 64) {
        float ev[24]; int iv[24];
#pragma unroll
        for (int s = 0; s < 24; ++s) { ev[s] = ce[t][s]; iv[s] = ci[t][s]; }
        unsigned mask = 0;
#pragma unroll
        for (int pass = 0; pass < 4; ++pass) {
            float best = -3.4e38f; int bid = -1, bs = 0;
#pragma unroll
            for (int s = 0; s < 24; ++s) {
                bool free_ = ((mask >> s) & 1u) == 0u;
                bool gt = (ev[s] > best) || (ev[s] == best && iv[s] > bid);
                if (free_ && gt) { best = ev[s]; bid = iv[s]; bs = s; }
            }
            mask |= 1u << bs;
        }
        int* op = knn_idx + (size_t)(n0 + t) * KNN;
        int pos = 0;
#pragma unroll
        for (int s = 0; s < 24; ++s)
            if (((mask >> s) & 1u) == 0u) op[pos++] = iv[s];
    }
}

// ---------------- fused edge MLP ----------------
__device__ __forceinline__ void gemm_tile(const unsigned short* A, const unsigned short* Bw,
                                          int wv, int lane, f32x4 acc[2][8]) {
    int lr = lane & 15, kg = lane >> 4;
#pragma unroll
    for (int ks = 0; ks < 4; ++ks) {
        int ko = ks * 32 + kg * 8;
        bf16x8 a0 = *(const bf16x8*)(A + (size_t)(wv * 32 + lr) * LDA + ko);
        bf16x8 a1 = *(const bf16x8*)(A + (size_t)(wv * 32 + 16 + lr) * LDA + ko);
#pragma unroll
        for (int nt = 0; nt < 8; ++nt) {
            bf16x8 bf = *(const bf16x8*)(Bw + (size_t)(nt * 16 + lr) * LDA + ko);
            acc[0][nt] = __builtin_amdgcn_mfma_f32_16x16x32_bf16(a0, bf, acc[0][nt], 0, 0, 0);
            acc[1][nt] = __builtin_amdgcn_mfma_f32_16x16x32_bf16(a1, bf, acc[1][nt], 0, 0, 0);
        }
    }
}

__device__ __forceinline__ void ln_relu_store(f32x4 acc[2][8], unsigned short* A, int wv, int lane,
                                              const float* __restrict__ bias, const float* __restrict__ g,
                                              const float* __restrict__ be) {
    int lc = lane & 15, kg = lane >> 4;
    float bv[8], gv[8], bev[8];
#pragma unroll
    for (int nt = 0; nt < 8; ++nt) {
        bv[nt]  = bias[nt * 16 + lc];
        gv[nt]  = g[nt * 16 + lc];
        bev[nt] = be[nt * 16 + lc];
    }
#pragma unroll
    for (int mt = 0; mt < 2; ++mt) {
#pragma unroll
        for (int j = 0; j < 4; ++j) {
            float v[8]; float s = 0.f, ss = 0.f;
#pragma unroll
            for (int nt = 0; nt < 8; ++nt) {
                v[nt] = acc[mt][nt][j] + bv[nt];
                s += v[nt]; ss += v[nt] * v[nt];
            }
#pragma unroll
            for (int m = 1; m < 16; m <<= 1) { s += __shfl_xor(s, m); ss += __shfl_xor(ss, m); }
            float mean = s * 0.0078125f;                       // /128
            float var  = ss * 0.0078125f - mean * mean;
            float rstd = rsqrtf(fmaxf(var, 0.f) + 1e-5f);
            int row = wv * 32 + mt * 16 + kg * 4 + j;          // verified C layout
#pragma unroll
            for (int nt = 0; nt < 8; ++nt) {
                float h = (v[nt] - mean) * rstd * gv[nt] + bev[nt];
                h = fmaxf(h, 0.f);
                A[(size_t)row * LDA + nt * 16 + lc] = f2bf(h);
            }
        }
    }
}

__global__ __launch_bounds__(320) void k_edge(const float* __restrict__ x, const int* __restrict__ knn_idx,
                                              const unsigned short* __restrict__ w1t, const unsigned short* __restrict__ w2t,
                                              const float* __restrict__ b1, const float* __restrict__ g1, const float* __restrict__ be1,
                                              const float* __restrict__ b2, const float* __restrict__ g2, const float* __restrict__ be2,
                                              const float* __restrict__ Wres, const float* __restrict__ bres,
                                              float* __restrict__ out) {
    __shared__ unsigned short A[160 * LDA];    // 43520 B: e-tile -> h1 -> h2
    __shared__ unsigned short Bw[128 * LDA];   // 34816 B: W1t then W2t
    int t = threadIdx.x;
    int blk = blockIdx.x;

    {
        int r = t >> 1, half = t & 1;
        int eg = blk * 160 + r;
        int n = eg / 20;
        int j = knn_idx[eg];
        const float* xi = x + (size_t)n * 64;
        if (half == 0) {
#pragma unroll
            for (int i = 0; i < 16; ++i) {
                float4 v = *(const float4*)(xi + i * 4);
                ushort4 pk; pk.x = f2bf(v.x); pk.y = f2bf(v.y); pk.z = f2bf(v.z); pk.w = f2bf(v.w);
                *(ushort4*)&A[(size_t)r * LDA + i * 4] = pk;
            }
        } else {
            const float* xj = x + (size_t)j * 64;
#pragma unroll
            for (int i = 0; i < 16; ++i) {
                float4 vi = *(const float4*)(xi + i * 4);
                float4 vj = *(const float4*)(xj + i * 4);
                ushort4 pk; pk.x = f2bf(vj.x - vi.x); pk.y = f2bf(vj.y - vi.y);
                pk.z = f2bf(vj.z - vi.z); pk.w = f2bf(vj.w - vi.w);
                *(ushort4*)&A[(size_t)r * LDA + 64 + i * 4] = pk;
            }
        }
    }
    for (int id = t; id < 2048; id += 320) {
        int row = id >> 4, ch = id & 15;
        *(uint4*)&Bw[(size_t)row * LDA + ch * 8] = *(const uint4*)(w1t + (size_t)row * 128 + ch * 8);
    }
    __syncthreads();

    int wv = t >> 6, lane = t & 63;
    f32x4 acc[2][8];
#pragma unroll
    for (int i = 0; i < 2; ++i)
#pragma unroll
        for (int j = 0; j < 8; ++j) acc[i][j] = (f32x4){0.f, 0.f, 0.f, 0.f};
    gemm_tile(A, Bw, wv, lane, acc);
    ln_relu_store(acc, A, wv, lane, b1, g1, be1);
    __syncthreads();
    for (int id = t; id < 2048; id += 320) {
        int row = id >> 4, ch = id & 15;
        *(uint4*)&Bw[(size_t)row * LDA + ch * 8] = *(const uint4*)(w2t + (size_t)row * 128 + ch * 8);
    }
    __syncthreads();

    f32x4 acc2[2][8];
#pragma unroll
    for (int i = 0; i < 2; ++i)
#pragma unroll
        for (int j = 0; j < 8; ++j) acc2[i][j] = (f32x4){0.f, 0.f, 0.f, 0.f};
    gemm_tile(A, Bw, wv, lane, acc2);
    ln_relu_store(acc2, A, wv, lane, b2, g2, be2);
    __syncthreads();

    for (int i = t; i < 1024; i += 320) {
        int p = i >> 7, c = i & 127;
        float mx = 0.f;
#pragma unroll
        for (int r = 0; r < 20; ++r)
            mx = fmaxf(mx, bf2f(A[(size_t)(p * 20 + r) * LDA + c]));
        int n = blk * 8 + p;
        float accr = bres[c];
        const float* xr = x + (size_t)n * 64;
#pragma unroll 8
        for (int cc = 0; cc < 64; ++cc) accr += xr[cc] * Wres[(size_t)cc * 128 + c];
        out[(size_t)n * 128 + c] = mx + accr;
    }
}

// ---------------- launcher ----------------
extern "C" void kernel_launch(void* const* d_in, const int* in_sizes, int n_in,
                              void* d_out, int out_size, void* d_ws, size_t ws_size,
                              hipStream_t stream) {
    const float* x    = (const float*)d_in[0];
    const float* W1   = (const float*)d_in[2];
    const float* b1   = (const float*)d_in[3];
    const float* g1   = (const float*)d_in[4];
    const float* be1  = (const float*)d_in[5];
    const float* W2   = (const float*)d_in[6];
    const float* b2   = (const float*)d_in[7];
    const float* g2   = (const float*)d_in[8];
    const float* be2  = (const float*)d_in[9];
    const float* Wres = (const float*)d_in[10];
    const float* bres = (const float*)d_in[11];
    float* out = (float*)d_out;

    char* ws = (char*)d_ws;
    float* sq            = (float*)(ws);                    // 131072 B
    unsigned short* w1t  = (unsigned short*)(ws + 131072);  // 32768 B
    unsigned short* w2t  = (unsigned short*)(ws + 163840);  // 32768 B
    int* knn_idx         = (int*)(ws + 196608);             // 2621440 B  (total ~2.8 MB)

    // bf16 hi/lo planes staged inside d_out (16.78 MB >= 8.39 MB), consumed before k_edge writes
    unsigned short* xhi = (unsigned short*)d_out;                       // 4 MB
    unsigned short* xlo = (unsigned short*)((char*)d_out + 4194304);    // 4 MB

    k_prep <<<dim3(1024),     dim3(256), 0, stream>>>(x, xhi, xlo);
    k_sq   <<<dim3(NTOT / 4), dim3(256), 0, stream>>>(x, sq);
    k_wt   <<<dim3(128),      dim3(256), 0, stream>>>(W1, W2, w1t, w2t);
    k_knn  <<<dim3(NB * 64),  dim3(256), 0, stream>>>(x, xhi, xlo, sq, knn_idx);
    k_edge <<<dim3(NEDGE / 160), dim3(320), 0, stream>>>(x, knn_idx, w1t, w2t,
                                                         b1, g1, be1, b2, g2, be2,
                                                         Wres, bres, out);
}